// Round 11
// baseline (1765.488 us; speedup 1.0000x reference)
//
#include <hip/hip_runtime.h>

// EncoderPlanarLSTM: T=256,B=1024,DX=48,DA=16 (I=64), H=512, Z=32, F=4
// out = [mu(1024x32) | log_var(1024x32) | u(1024x128) | w(1024x128) | b(1024x4)] fp32
//
// R11: deferred-drain pipeline. Half h: MFMA/gates (previous half's publish acks in
// background) -> free vmcnt(0) -> barrier -> flag(tag=h) -> poll peers(tag=h) ->
// h-loads -> publish (flies through next half) -> stage -> barrier. XCD-local groups
// (xcd = wg%8, FETCH-validated in R10); sc0 sc1 exchange protocol unchanged from R10.

typedef __attribute__((__ext_vector_type__(8))) short bx8;   // 8 bf16 (4 VGPR)
typedef __attribute__((__ext_vector_type__(4))) float fx4;
typedef __attribute__((__ext_vector_type__(4))) unsigned ux4;
typedef unsigned long long u64;

#define NSTEP 256
#define NKT   18          // K-tiles of 32 over K=576 (512 h + 64 y)
#define ROWB  1184        // LDS bytes per A row (1152 data + 32 pad)
#define GREG  18944       // per-group LDS region: 16 rows * 1184
#define TRPO  37888       // transpose slabs at 2*GREG

__device__ __forceinline__ short bf16_of(float f) {
  union { float f; unsigned u; } c; c.f = f;
  unsigned r = c.u + 0x7fffu + ((c.u >> 16) & 1u);   // RNE
  return (short)(r >> 16);
}
__device__ __forceinline__ float fsigmoid(float x) {
  float e = __builtin_amdgcn_exp2f(-1.44269504f * x);
  return __builtin_amdgcn_rcpf(1.0f + e);
}
__device__ __forceinline__ float ftanh_(float x) {
  float e = __builtin_amdgcn_exp2f(2.88539008f * x);
  return 1.0f - 2.0f * __builtin_amdgcn_rcpf(1.0f + e);
}

__device__ __forceinline__ void poll_flags(const unsigned* p, unsigned tgt) {
  unsigned guard = 0;
  for (;;) {
    unsigned v;
    asm volatile("global_load_dword %0, %1, off sc0 sc1\n\ts_waitcnt vmcnt(0)"
                 : "=v"(v) : "v"(p) : "memory");
    if (__all((int)(v >= tgt))) break;
    if (++guard > (1u << 16)) break;      // bail: terminate, never hang
  }
}

// ---------------- pack masked+concat input to bf16, natural time order -------
__global__ __launch_bounds__(256) void pack_y_kernel(
    const float* __restrict__ x, const float* __restrict__ a,
    const float* __restrict__ mk, short* __restrict__ y) {
  const int idx = blockIdx.x * 256 + threadIdx.x;
  const float* xp = x + (size_t)idx * 48;
  const float* mp = mk + (size_t)idx * 48;
  const float* ap = a + (size_t)idx * 16;
  short* yp = y + (size_t)idx * 64;
  float v[64];
#pragma unroll
  for (int j = 0; j < 12; ++j) {
    fx4 xv = *(const fx4*)(xp + j * 4);
    fx4 mv = *(const fx4*)(mp + j * 4);
#pragma unroll
    for (int t = 0; t < 4; ++t) v[j * 4 + t] = xv[t] * mv[t];
  }
#pragma unroll
  for (int j = 0; j < 4; ++j) {
    fx4 av = *(const fx4*)(ap + j * 4);
#pragma unroll
    for (int t = 0; t < 4; ++t) v[48 + j * 4 + t] = av[t];
  }
#pragma unroll
  for (int c = 0; c < 8; ++c) {
    bx8 o;
#pragma unroll
    for (int t = 0; t < 8; ++t) o[t] = bf16_of(v[c * 8 + t]);
    *(bx8*)(yp + c * 8) = o;
  }
}

// ---------------- one half: compute X, flag prev publish, prefetch Y ---------
__device__ __forceinline__ void do_half(
    unsigned tag, bool pub, bool pref, bool fin,
    int gX, int gY, char* Ash, int regX, int regY, char* trpX,
    const bx8* Bf, const float* bias, float* cstX,
    const short* yslY, const char* hsrcY, char* hdstX,
    float* __restrict__ hfinal, unsigned* myflag, const unsigned* pollp,
    int tid, int wv, int l15, int l4, int srow, int sch,
    unsigned xsw, unsigned xm, int colh, int gn)
{
  // 0: Y's y-input (plain load, compiler-tracked; hides under MFMA — R8-proven)
  u64 vy = 0;
  if (pref)
    vy = *(const u64*)((const char*)yslY + (size_t)(gY * 16 + srow) * 128 + sch * 8);

  // 1: MFMA X; previous half's publish stores are acking in the background
  fx4 acc[4];
#pragma unroll
  for (int nt = 0; nt < 4; ++nt) {
    fx4 z = {bias[nt], bias[nt], bias[nt], bias[nt]};
    acc[nt] = z;
  }
  const char* abase = Ash + regX + l15 * ROWB;
  const unsigned kbase = (unsigned)(l4 * 16);
#pragma unroll
  for (int kt = 0; kt < NKT; ++kt) {
    bx8 A0 = *(const bx8*)(abase + (int)(((unsigned)(kt * 64) + kbase) ^ xm));
#pragma unroll
    for (int nt = 0; nt < 4; ++nt)
      acc[nt] = __builtin_amdgcn_mfma_f32_16x16x32_bf16(A0, Bf[nt * NKT + kt], acc[nt], 0, 0, 0);
  }

  // 2: gates + state update
  unsigned hs16[4];
#pragma unroll
  for (int r = 0; r < 4; ++r) {
    float gi = acc[0][r], gf = acc[1][r], gg = acc[2][r], go = acc[3][r];
    float c = fsigmoid(gf) * cstX[r] + fsigmoid(gi) * ftanh_(gg);
    cstX[r] = c;
    float h = fsigmoid(go) * ftanh_(c);
    hs16[r] = (unsigned)(unsigned short)bf16_of(h);
    if (fin) hfinal[(size_t)(gX * 16 + l4 * 4 + r) * 512 + colh] = h;
  }

  // 3: trp-write X (LDS transpose for coalesced publish)
  if (pub) {
#pragma unroll
    for (int r = 0; r < 4; ++r)
      *(unsigned short*)(trpX + (l4 * 4 + r) * 128 + (wv * 16 + l15) * 2) =
          (unsigned short)hs16[r];
  }

  if (!pub && !pref) return;   // terminal half: kernel-end drain handles stores

  // 4: FREE drain — previous publish has been in flight for a whole compute phase
  asm volatile("s_waitcnt vmcnt(0) lgkmcnt(0)" ::: "memory");
  __builtin_amdgcn_sched_barrier(0);
  __builtin_amdgcn_s_barrier();

  // 5: announce previous half's publish (tag = half index, monotone)
  if (tid == 0) {
    unsigned sv = tag;
    asm volatile("global_store_dword %0, %1, off sc0 sc1" :: "v"(myflag), "v"(sv) : "memory");
  }

  // 6/7: poll peers (wrote at their step 5, ~synchronized), then issue h-loads
  ux4 vh0, vh1, vh2, vh3;
  if (pref) {
    poll_flags(pollp, tag);
    const char* hq = hsrcY + (size_t)(gY * 16 + srow) * 1024 + sch * 16;
    asm volatile("global_load_dwordx4 %0, %1, off sc0 sc1" : "=v"(vh0) : "v"(hq) : "memory");
    asm volatile("global_load_dwordx4 %0, %1, off offset:256 sc0 sc1" : "=v"(vh1) : "v"(hq) : "memory");
    asm volatile("global_load_dwordx4 %0, %1, off offset:512 sc0 sc1" : "=v"(vh2) : "v"(hq) : "memory");
    asm volatile("global_load_dwordx4 %0, %1, off offset:768 sc0 sc1" : "=v"(vh3) : "v"(hq) : "memory");
  }

  // 8: publish X h AFTER the loads (in-order vmcnt retirement) — flies into next half
  if (pub) {
    u64 pv = *(const u64*)(trpX + srow * 128 + sch * 8);
    char* sb = hdstX + (size_t)(gX * 16 + srow) * 1024 + gn * 128 + sch * 8;
    asm volatile("global_store_dwordx2 %0, %1, off sc0 sc1" :: "v"(sb), "v"(pv) : "memory");
  }

  // 9: wait loads only (publish stays outstanding), stage Y into LDS
  if (pref) {
    if (pub) asm volatile("s_waitcnt vmcnt(1)" ::: "memory");
    else     asm volatile("s_waitcnt vmcnt(0)" ::: "memory");
    __builtin_amdgcn_sched_barrier(0);
    char* lb = Ash + regY + srow * ROWB;
    *(ux4*)(lb + (int)(((unsigned)(sch * 16 + 0))   ^ xsw)) = vh0;
    *(ux4*)(lb + (int)(((unsigned)(sch * 16 + 256)) ^ xsw)) = vh1;
    *(ux4*)(lb + (int)(((unsigned)(sch * 16 + 512)) ^ xsw)) = vh2;
    *(ux4*)(lb + (int)(((unsigned)(sch * 16 + 768)) ^ xsw)) = vh3;
    *(u64*)(lb + (int)((1024u + sch * 8) ^ xsw)) = vy;
  }

  // 10: close: stage visible; publish remains in flight (drained next half, free)
  asm volatile("s_waitcnt lgkmcnt(0)" ::: "memory");
  __builtin_amdgcn_sched_barrier(0);
  __builtin_amdgcn_s_barrier();
}

// ---------------- recurrent LSTM, 2-group interleaved, weight-stationary -----
__global__ __launch_bounds__(256, 1) void lstm_rec(
    const short* __restrict__ yw,      // [256][1024][64] bf16
    const float* __restrict__ w_hh,    // [2048][512]
    const float* __restrict__ w_ih,    // [2048][64]
    const float* __restrict__ b_ih, const float* __restrict__ b_hh,
    short* hbuf,                       // [2][1024][512] bf16
    float* __restrict__ hfinal,        // [1024][512]
    unsigned* ctr)                     // flag words at u32[1024 + (pod*8+gn)*16]
{
  __shared__ __align__(16) char Ash[82432];   // >81920 -> exactly 1 WG/CU
  const int tid = threadIdx.x;
  const int wg  = blockIdx.x;
  // ---- XCD-local mapping (R10 FETCH-validated): all 8 slices on one XCD ----
  const int xcd = wg & 7;
  const int ii  = wg >> 3;             // 0..31 within XCD
  const int gn  = ii & 7;              // 64-col slice
  const int q   = ii >> 3;             // pod 0..3 within XCD
  const int gA  = xcd * 4 + q;         // 0..31
  const int gB  = gA + 32;
  const int wv  = tid >> 6;
  const int lane = tid & 63;
  const int l15 = lane & 15;
  const int l4  = lane >> 4;

  // ---- resident weights: 4 gates x 18 kt, cols gn*64 + wv*16 + l15 ----
  bx8 Bf[4 * NKT];
  float bias[4];
  const int colh = gn * 64 + wv * 16 + l15;
#pragma unroll
  for (int nt = 0; nt < 4; ++nt) {
    const int col = nt * 512 + colh;
    bias[nt] = b_ih[col] + b_hh[col];
#pragma unroll
    for (int kt = 0; kt < NKT; ++kt) {
      const int k0 = kt * 32 + l4 * 8;
      const float* src = (k0 < 512) ? (w_hh + (size_t)col * 512 + k0)
                                    : (w_ih + (size_t)col * 64 + (k0 - 512));
      fx4 w0 = *(const fx4*)(src);
      fx4 w1 = *(const fx4*)(src + 4);
      bx8 b;
#pragma unroll
      for (int t = 0; t < 4; ++t) { b[t] = bf16_of(w0[t]); b[4 + t] = bf16_of(w1[t]); }
      Bf[nt * NKT + kt] = b;
    }
  }

  float cstA[4], cstB[4];
#pragma unroll
  for (int i = 0; i < 4; ++i) { cstA[i] = 0.f; cstB[i] = 0.f; }

  const int srow = tid >> 4;           // 0..15: staging/publish row
  const int sch  = tid & 15;
  const unsigned xsw = (unsigned)((srow & 7) << 4);
  const unsigned xm  = (unsigned)((l15 & 7) << 4);
  char* trpA = Ash + TRPO;
  char* trpB = Ash + TRPO + 2048;

  unsigned* flbase = ctr + 1024;
  unsigned* myflag = flbase + (gA * 8 + gn) * 16;            // one word/WG, monotone tag
  const unsigned* pollp = flbase + (gA * 8 + (lane & 7)) * 16;

  // ---- prologue: stage A(0) (h=0 from memset; plain compiler-tracked loads) --
  {
    u64 vy = *(const u64*)((const char*)(yw + (size_t)255 * 65536) +
                           (size_t)(gA * 16 + srow) * 128 + sch * 8);
    const u64* hq = (const u64*)((const char*)hbuf + (size_t)(gA * 16 + srow) * 1024) + sch * 2;
    char* lb = Ash + srow * ROWB;
#pragma unroll
    for (int j = 0; j < 4; ++j) {
      u64 a = hq[j * 32], b = hq[j * 32 + 1];
      *(u64*)(lb + (int)(((unsigned)(sch * 16 + j * 256))     ^ xsw)) = a;
      *(u64*)(lb + (int)(((unsigned)(sch * 16 + j * 256 + 8)) ^ xsw)) = b;
    }
    *(u64*)(lb + (int)((1024u + sch * 8) ^ xsw)) = vy;
    asm volatile("s_waitcnt lgkmcnt(0)" ::: "memory");
    __builtin_amdgcn_sched_barrier(0);
    __builtin_amdgcn_s_barrier();
  }

#pragma unroll 1
  for (int s = 0; s < NSTEP; ++s) {
    char* sl0 = (char*)hbuf + (size_t)(s & 1) * 1048576;        // h(s)
    char* sl1 = (char*)hbuf + (size_t)((s + 1) & 1) * 1048576;  // h(s+1)
    const short* ysB = yw + (size_t)(255 - s) * 65536;
    const short* ysA = yw + (size_t)(s < 255 ? 254 - s : 0) * 65536;
    const bool last = (s == NSTEP - 1);
    // half 2s: compute A(s); flag prev B-publish; stage B(s) from sl0; publish A h(s+1)->sl1
    do_half((unsigned)(2 * s), !last, true, last,
            gA, gB, Ash, 0, GREG, trpA, Bf, bias, cstA,
            ysB, sl0, sl1, hfinal, myflag, pollp,
            tid, wv, l15, l4, srow, sch, xsw, xm, colh, gn);
    // half 2s+1: compute B(s); flag A-publish; stage A(s+1) from sl1; publish B h(s+1)->sl1
    do_half((unsigned)(2 * s + 1), !last, !last, last,
            gB, gA, Ash, GREG, 0, trpB, Bf, bias, cstB,
            ysA, sl1, sl1, hfinal, myflag, pollp,
            tid, wv, l15, l4, srow, sch, xsw, xm, colh, gn);
  }
}

// ---------------- heads: exact fp32 VALU GEMM [1024 x 324 x 512] + epilogue --
__global__ __launch_bounds__(256) void heads_kernel(
    const float* __restrict__ hf,
    const float* __restrict__ lin_w, const float* __restrict__ lin_b,
    const float* __restrict__ lv_w,  const float* __restrict__ lv_b,
    const float* __restrict__ u_w,   const float* __restrict__ u_b,
    const float* __restrict__ ww_w,  const float* __restrict__ ww_b,
    const float* __restrict__ bf_w,  const float* __restrict__ bf_b,
    float* __restrict__ out)
{
  __shared__ float hs[64 * 513];
  const int tid = threadIdx.x;
  const int gb = blockIdx.x;     // 0..15
  const int cg = blockIdx.y;     // 0..5, 54 cols each
  for (int i = tid; i < 8192; i += 256) {
    fx4 v = *(const fx4*)(hf + (size_t)gb * 32768 + (size_t)i * 4);
    const int row = i >> 7;
    const int k = (i * 4) & 511;
    float* d = hs + row * 513 + k;
    d[0] = v[0]; d[1] = v[1]; d[2] = v[2]; d[3] = v[3];
  }
  __syncthreads();
  const int r = tid & 63;
  const int cq = tid >> 6;
  const float* hrow = hs + r * 513;
  const int b_ = gb * 64 + r;
#pragma unroll 1
  for (int j = 0; j < 14; ++j) {
    const int cl = cq + 4 * j;
    if (cl >= 54) break;
    const int C = cg * 54 + cl;      // 0..323
    const float* wp; float bv;
    if (C < 32)       { wp = lin_w + (size_t)C * 512;        bv = lin_b[C]; }
    else if (C < 64)  { wp = lv_w + (size_t)(C - 32) * 512;  bv = lv_b[C - 32]; }
    else if (C < 192) { wp = u_w + (size_t)(C - 64) * 512;   bv = u_b[C - 64]; }
    else if (C < 320) { wp = ww_w + (size_t)(C - 192) * 512; bv = ww_b[C - 192]; }
    else              { wp = bf_w + (size_t)(C - 320) * 512; bv = bf_b[C - 320]; }
    float dot = 0.f;
#pragma unroll 8
    for (int k = 0; k < 512; k += 4) {
      fx4 w = *(const fx4*)(wp + k);
      dot += hrow[k] * w[0] + hrow[k + 1] * w[1] + hrow[k + 2] * w[2] + hrow[k + 3] * w[3];
    }
    const float res = bv + dot;
    if (C < 32)       out[(size_t)b_ * 32 + C] = __builtin_amdgcn_exp2f(res * 1.44269504f) * 0.1f;
    else if (C < 64)  out[32768 + (size_t)b_ * 32 + (C - 32)] = res - 5.f;
    else if (C < 192) out[65536 + (size_t)b_ * 128 + (C - 64)] = res;
    else if (C < 320) out[196608 + (size_t)b_ * 128 + (C - 192)] = res;
    else              out[327680 + (size_t)b_ * 4 + (C - 320)] = res;
  }
}

extern "C" void kernel_launch(void* const* d_in, const int* in_sizes, int n_in,
                              void* d_out, int out_size, void* d_ws, size_t ws_size,
                              hipStream_t stream) {
  (void)in_sizes; (void)n_in; (void)out_size; (void)ws_size;
  const float* x     = (const float*)d_in[0];
  const float* a     = (const float*)d_in[1];
  const float* mask  = (const float*)d_in[2];
  const float* w_ih  = (const float*)d_in[3];
  const float* w_hh  = (const float*)d_in[4];
  const float* b_ih  = (const float*)d_in[5];
  const float* b_hh  = (const float*)d_in[6];
  const float* lin_w = (const float*)d_in[7];
  const float* lin_b = (const float*)d_in[8];
  const float* lv_w  = (const float*)d_in[9];
  const float* lv_b  = (const float*)d_in[10];
  const float* u_w   = (const float*)d_in[11];
  const float* u_b   = (const float*)d_in[12];
  const float* ww_w  = (const float*)d_in[13];
  const float* ww_b  = (const float*)d_in[14];
  const float* bf_w  = (const float*)d_in[15];
  const float* bf_b  = (const float*)d_in[16];

  char* ws = (char*)d_ws;
  short* yw       = (short*)(ws);                 // 33,554,432 B: [256][1024][64] bf16
  short* hbuf     = (short*)(ws + 33554432);      //  2,097,152 B: [2][1024][512] bf16
  float* hfinal   = (float*)(ws + 35651584);      //  2,097,152 B
  unsigned* ctr   = (unsigned*)(ws + 37748736);   //     36,864 B (flags region)

  hipMemsetAsync(hbuf, 0, 2097152, stream);       // both slots -> finite residue
  hipMemsetAsync(ctr, 0, 36864, stream);

  pack_y_kernel<<<1024, 256, 0, stream>>>(x, a, mask, yw);
  lstm_rec<<<256, 256, 0, stream>>>(yw, w_hh, w_ih, b_ih, b_hh, hbuf, hfinal, ctr);
  heads_kernel<<<dim3(16, 6), 256, 0, stream>>>(hfinal, lin_w, lin_b, lv_w, lv_b,
                                                u_w, u_b, ww_w, ww_b, bf_w, bf_b,
                                                (float*)d_out);
}

// Round 13
// 1499.020 us; speedup vs baseline: 1.1778x; 1.1778x over previous
//
#include <hip/hip_runtime.h>

// EncoderPlanarLSTM: T=256,B=1024,DX=48,DA=16 (I=64), H=512, Z=32, F=4
// out = [mu(1024x32) | log_var(1024x32) | u(1024x128) | w(1024x128) | b(1024x4)] fp32
//
// R13: merged-chain pipeline. 64 groups x 16 rows; WG=(pod gA=xcd*4+q, slice gn) owns
// gA and gB=gA+32 (XCD-local mapping, R10 FETCH-validated). Per step: compute A, compute
// B (MFMA from LDS, weights resident), then ONE exchange chain for both groups:
// publish h_A,h_B (sc0 sc1) -> vmcnt(0) -> barrier -> flag(s+1) -> poll -> load both ->
// stage both. All mechanisms byte-identical to R10; only the schedule merges.

typedef __attribute__((__ext_vector_type__(8))) short bx8;   // 8 bf16 (4 VGPR)
typedef __attribute__((__ext_vector_type__(4))) float fx4;
typedef __attribute__((__ext_vector_type__(4))) unsigned ux4;
typedef unsigned long long u64;

#define NKT   18          // K-tiles of 32 over K=576 (512 h + 64 y)
#define ROWB  1184        // LDS bytes per A row (1152 data + 32 pad)
#define GREG  18944       // per-group LDS region: 16 rows * 1184
#define TRPO  37888       // transpose slabs at 2*GREG

__device__ __forceinline__ short bf16_of(float f) {
  union { float f; unsigned u; } c; c.f = f;
  unsigned r = c.u + 0x7fffu + ((c.u >> 16) & 1u);   // RNE
  return (short)(r >> 16);
}
__device__ __forceinline__ float fsigmoid(float x) {
  float e = __builtin_amdgcn_exp2f(-1.44269504f * x);
  return __builtin_amdgcn_rcpf(1.0f + e);
}
__device__ __forceinline__ float ftanh_(float x) {
  float e = __builtin_amdgcn_exp2f(2.88539008f * x);
  return 1.0f - 2.0f * __builtin_amdgcn_rcpf(1.0f + e);
}

__device__ __forceinline__ void poll_flags(const unsigned* p, unsigned tgt) {
  unsigned guard = 0;
  for (;;) {
    unsigned v;
    asm volatile("global_load_dword %0, %1, off sc0 sc1\n\ts_waitcnt vmcnt(0)"
                 : "=v"(v) : "v"(p) : "memory");
    if (__all((int)(v >= tgt))) break;
    if (++guard > (1u << 16)) break;      // bail: terminate, never hang
  }
}

// ---------------- pack masked+concat input to bf16, natural time order -------
__global__ __launch_bounds__(256) void pack_y_kernel(
    const float* __restrict__ x, const float* __restrict__ a,
    const float* __restrict__ mk, short* __restrict__ y) {
  const int idx = blockIdx.x * 256 + threadIdx.x;
  const float* xp = x + (size_t)idx * 48;
  const float* mp = mk + (size_t)idx * 48;
  const float* ap = a + (size_t)idx * 16;
  short* yp = y + (size_t)idx * 64;
  float v[64];
#pragma unroll
  for (int j = 0; j < 12; ++j) {
    fx4 xv = *(const fx4*)(xp + j * 4);
    fx4 mv = *(const fx4*)(mp + j * 4);
#pragma unroll
    for (int t = 0; t < 4; ++t) v[j * 4 + t] = xv[t] * mv[t];
  }
#pragma unroll
  for (int j = 0; j < 4; ++j) {
    fx4 av = *(const fx4*)(ap + j * 4);
#pragma unroll
    for (int t = 0; t < 4; ++t) v[48 + j * 4 + t] = av[t];
  }
#pragma unroll
  for (int c = 0; c < 8; ++c) {
    bx8 o;
#pragma unroll
    for (int t = 0; t < 8; ++t) o[t] = bf16_of(v[c * 8 + t]);
    *(bx8*)(yp + c * 8) = o;
  }
}

// ---------------- compute one group: MFMA + gates + trp/hfinal ---------------
__device__ __forceinline__ void compute_grp(
    bool fin, char* Ash, int reg, char* trp,
    const bx8* Bf, const float* bias, float* cst,
    int g, int colh, int wv, int l15, int l4, unsigned xm,
    float* __restrict__ hfinal)
{
  fx4 acc[4];
#pragma unroll
  for (int nt = 0; nt < 4; ++nt) {
    fx4 z = {bias[nt], bias[nt], bias[nt], bias[nt]};
    acc[nt] = z;
  }
  const char* abase = Ash + reg + l15 * ROWB;
  const unsigned kbase = (unsigned)(l4 * 16);
#pragma unroll
  for (int kt = 0; kt < NKT; ++kt) {
    bx8 A0 = *(const bx8*)(abase + (int)(((unsigned)(kt * 64) + kbase) ^ xm));
#pragma unroll
    for (int nt = 0; nt < 4; ++nt)
      acc[nt] = __builtin_amdgcn_mfma_f32_16x16x32_bf16(A0, Bf[nt * NKT + kt], acc[nt], 0, 0, 0);
  }
#pragma unroll
  for (int r = 0; r < 4; ++r) {
    float gi = acc[0][r], gf = acc[1][r], gg = acc[2][r], go = acc[3][r];
    float c = fsigmoid(gf) * cst[r] + fsigmoid(gi) * ftanh_(gg);
    cst[r] = c;
    float h = fsigmoid(go) * ftanh_(c);
    if (fin) {
      hfinal[(size_t)(g * 16 + l4 * 4 + r) * 512 + colh] = h;
    } else {
      *(unsigned short*)(trp + (l4 * 4 + r) * 128 + (wv * 16 + l15) * 2) =
          (unsigned short)bf16_of(h);
    }
  }
}

// ---------------- recurrent LSTM: merged per-step exchange -------------------
__global__ __launch_bounds__(256, 1) void lstm_rec(
    const short* __restrict__ yw,      // [256][1024][64] bf16
    const float* __restrict__ w_hh,    // [2048][512]
    const float* __restrict__ w_ih,    // [2048][64]
    const float* __restrict__ b_ih, const float* __restrict__ b_hh,
    short* hbuf,                       // [2][1024][512] bf16 (kernel-written only)
    float* __restrict__ hfinal,        // [1024][512]
    unsigned* ctr)                     // flag words at u32[1024 + (gA*8+gn)*16]
{
  __shared__ __align__(16) char Ash[82432];   // >81920 -> exactly 1 WG/CU
  const int tid = threadIdx.x;
  const int wg  = blockIdx.x;
  // XCD-local mapping (R10 FETCH-validated): all 8 slices of a pod on one XCD
  const int xcd = wg & 7;
  const int ii  = wg >> 3;
  const int gn  = ii & 7;              // 64-col slice
  const int q   = ii >> 3;             // pod 0..3 within XCD
  const int gA  = xcd * 4 + q;         // 0..31
  const int gB  = gA + 32;
  const int wv  = tid >> 6;
  const int lane = tid & 63;
  const int l15 = lane & 15;
  const int l4  = lane >> 4;

  // ---- resident weights: 4 gates x 18 kt, cols gn*64 + wv*16 + l15 ----
  bx8 Bf[4 * NKT];
  float bias[4];
  const int colh = gn * 64 + wv * 16 + l15;
#pragma unroll
  for (int nt = 0; nt < 4; ++nt) {
    const int col = nt * 512 + colh;
    bias[nt] = b_ih[col] + b_hh[col];
#pragma unroll
    for (int kt = 0; kt < NKT; ++kt) {
      const int k0 = kt * 32 + l4 * 8;
      const float* src = (k0 < 512) ? (w_hh + (size_t)col * 512 + k0)
                                    : (w_ih + (size_t)col * 64 + (k0 - 512));
      fx4 w0 = *(const fx4*)(src);
      fx4 w1 = *(const fx4*)(src + 4);
      bx8 b;
#pragma unroll
      for (int t = 0; t < 4; ++t) { b[t] = bf16_of(w0[t]); b[4 + t] = bf16_of(w1[t]); }
      Bf[nt * NKT + kt] = b;
    }
  }

  float cstA[4], cstB[4];
#pragma unroll
  for (int i = 0; i < 4; ++i) { cstA[i] = 0.f; cstB[i] = 0.f; }

  const int srow = tid >> 4;           // 0..15: staging/publish row
  const int sch  = tid & 15;
  const unsigned xsw = (unsigned)((srow & 7) << 4);
  const unsigned xm  = (unsigned)((l15 & 7) << 4);
  char* trpA = Ash + TRPO;
  char* trpB = Ash + TRPO + 2048;

  unsigned* flbase = ctr + 1024;
  unsigned* myflag = flbase + (gA * 8 + gn) * 16;
  const unsigned* pollp = flbase + (gA * 8 + (lane & 7)) * 16;

  // ---- prologue: stage regA/regB = zeros (h(0)=0) + y(255); no hbuf read ----
  {
    const char* ysl = (const char*)yw + (size_t)255 * 131072;
#pragma unroll
    for (int g2 = 0; g2 < 2; ++g2) {
      const int g = g2 ? gB : gA;
      const int reg = g2 ? GREG : 0;
      u64 vy = *(const u64*)(ysl + (size_t)(g * 16 + srow) * 128 + sch * 8);
      char* lb = Ash + reg + srow * ROWB;
      ux4 z = {0u, 0u, 0u, 0u};
#pragma unroll
      for (int j = 0; j < 4; ++j)
        *(ux4*)(lb + (int)(((unsigned)(sch * 16 + j * 256)) ^ xsw)) = z;
      *(u64*)(lb + (int)((1024u + sch * 8) ^ xsw)) = vy;
    }
    asm volatile("s_waitcnt lgkmcnt(0)" ::: "memory");
    __builtin_amdgcn_sched_barrier(0);
    __builtin_amdgcn_s_barrier();
  }

#pragma unroll 1
  for (int s = 0; s < 256; ++s) {
    const bool last = (s == 255);

    // early y loads for step s+1 (plain, compiler-tracked; hide under MFMA)
    const char* ynx = (const char*)yw + (size_t)(last ? 0 : 254 - s) * 131072;
    u64 vyA = *(const u64*)(ynx + (size_t)(gA * 16 + srow) * 128 + sch * 8);
    u64 vyB = *(const u64*)(ynx + (size_t)(gB * 16 + srow) * 128 + sch * 8);

    // compute both groups from staged LDS
    compute_grp(last, Ash, 0,    trpA, Bf, bias, cstA, gA, colh, wv, l15, l4, xm, hfinal);
    compute_grp(last, Ash, GREG, trpB, Bf, bias, cstB, gB, colh, wv, l15, l4, xm, hfinal);
    asm volatile("s_waitcnt lgkmcnt(0)" ::: "memory");
    __builtin_amdgcn_sched_barrier(0);
    __builtin_amdgcn_s_barrier();

    if (!last) {
      char* slot = (char*)hbuf + (size_t)((s + 1) & 1) * 1048576;

      // ---- publish h_A(s+1), h_B(s+1): coalesced 8B sc0 sc1 stores ----
      u64 pA = *(const u64*)(trpA + srow * 128 + sch * 8);
      u64 pB = *(const u64*)(trpB + srow * 128 + sch * 8);
      char* sbA = slot + (size_t)(gA * 16 + srow) * 1024 + gn * 128 + sch * 8;
      char* sbB = slot + (size_t)(gB * 16 + srow) * 1024 + gn * 128 + sch * 8;
      asm volatile("global_store_dwordx2 %0, %1, off sc0 sc1" :: "v"(sbA), "v"(pA) : "memory");
      asm volatile("global_store_dwordx2 %0, %1, off sc0 sc1" :: "v"(sbB), "v"(pB) : "memory");
      asm volatile("s_waitcnt vmcnt(0)" ::: "memory");   // both acked at MALL
      __builtin_amdgcn_s_barrier();                      // WG-wide publish complete

      // ---- one flag + one poll per step ----
      if (tid == 0) {
        unsigned sv = (unsigned)(s + 1);
        asm volatile("global_store_dword %0, %1, off sc0 sc1" :: "v"(myflag), "v"(sv) : "memory");
      }
      poll_flags(pollp, (unsigned)(s + 1));

      // ---- load h(s+1) for both groups (short-liveness asm; poll precedes) ----
      const char* hqA = slot + (size_t)(gA * 16 + srow) * 1024 + sch * 16;
      const char* hqB = slot + (size_t)(gB * 16 + srow) * 1024 + sch * 16;
      ux4 a0, a1, a2, a3, b0, b1, b2, b3;
      asm volatile("global_load_dwordx4 %0, %1, off sc0 sc1" : "=v"(a0) : "v"(hqA) : "memory");
      asm volatile("global_load_dwordx4 %0, %1, off offset:256 sc0 sc1" : "=v"(a1) : "v"(hqA) : "memory");
      asm volatile("global_load_dwordx4 %0, %1, off offset:512 sc0 sc1" : "=v"(a2) : "v"(hqA) : "memory");
      asm volatile("global_load_dwordx4 %0, %1, off offset:768 sc0 sc1" : "=v"(a3) : "v"(hqA) : "memory");
      asm volatile("global_load_dwordx4 %0, %1, off sc0 sc1" : "=v"(b0) : "v"(hqB) : "memory");
      asm volatile("global_load_dwordx4 %0, %1, off offset:256 sc0 sc1" : "=v"(b1) : "v"(hqB) : "memory");
      asm volatile("global_load_dwordx4 %0, %1, off offset:512 sc0 sc1" : "=v"(b2) : "v"(hqB) : "memory");
      asm volatile("global_load_dwordx4 %0, %1, off offset:768 sc0 sc1" : "=v"(b3) : "v"(hqB) : "memory");
      asm volatile("s_waitcnt vmcnt(0)" ::: "memory");
      __builtin_amdgcn_sched_barrier(0);

      // ---- stage both groups + y into LDS (R10-proven layout/swizzle) ----
      char* lbA = Ash + srow * ROWB;
      char* lbB = Ash + GREG + srow * ROWB;
      *(ux4*)(lbA + (int)(((unsigned)(sch * 16 + 0))   ^ xsw)) = a0;
      *(ux4*)(lbA + (int)(((unsigned)(sch * 16 + 256)) ^ xsw)) = a1;
      *(ux4*)(lbA + (int)(((unsigned)(sch * 16 + 512)) ^ xsw)) = a2;
      *(ux4*)(lbA + (int)(((unsigned)(sch * 16 + 768)) ^ xsw)) = a3;
      *(u64*)(lbA + (int)((1024u + sch * 8) ^ xsw)) = vyA;
      *(ux4*)(lbB + (int)(((unsigned)(sch * 16 + 0))   ^ xsw)) = b0;
      *(ux4*)(lbB + (int)(((unsigned)(sch * 16 + 256)) ^ xsw)) = b1;
      *(ux4*)(lbB + (int)(((unsigned)(sch * 16 + 512)) ^ xsw)) = b2;
      *(ux4*)(lbB + (int)(((unsigned)(sch * 16 + 768)) ^ xsw)) = b3;
      *(u64*)(lbB + (int)((1024u + sch * 8) ^ xsw)) = vyB;
      asm volatile("s_waitcnt lgkmcnt(0)" ::: "memory");
      __builtin_amdgcn_sched_barrier(0);
      __builtin_amdgcn_s_barrier();
    }
  }
}

// ---------------- heads: exact fp32 VALU GEMM [1024 x 324 x 512] + epilogue --
__global__ __launch_bounds__(256) void heads_kernel(
    const float* __restrict__ hf,
    const float* __restrict__ lin_w, const float* __restrict__ lin_b,
    const float* __restrict__ lv_w,  const float* __restrict__ lv_b,
    const float* __restrict__ u_w,   const float* __restrict__ u_b,
    const float* __restrict__ ww_w,  const float* __restrict__ ww_b,
    const float* __restrict__ bf_w,  const float* __restrict__ bf_b,
    float* __restrict__ out)
{
  __shared__ float hs[64 * 513];
  const int tid = threadIdx.x;
  const int gb = blockIdx.x;     // 0..15
  const int cg = blockIdx.y;     // 0..5, 54 cols each
  for (int i = tid; i < 8192; i += 256) {
    fx4 v = *(const fx4*)(hf + (size_t)gb * 32768 + (size_t)i * 4);
    const int row = i >> 7;
    const int k = (i * 4) & 511;
    float* d = hs + row * 513 + k;
    d[0] = v[0]; d[1] = v[1]; d[2] = v[2]; d[3] = v[3];
  }
  __syncthreads();
  const int r = tid & 63;
  const int cq = tid >> 6;
  const float* hrow = hs + r * 513;
  const int b_ = gb * 64 + r;
#pragma unroll 1
  for (int j = 0; j < 14; ++j) {
    const int cl = cq + 4 * j;
    if (cl >= 54) break;
    const int C = cg * 54 + cl;      // 0..323
    const float* wp; float bv;
    if (C < 32)       { wp = lin_w + (size_t)C * 512;        bv = lin_b[C]; }
    else if (C < 64)  { wp = lv_w + (size_t)(C - 32) * 512;  bv = lv_b[C - 32]; }
    else if (C < 192) { wp = u_w + (size_t)(C - 64) * 512;   bv = u_b[C - 64]; }
    else if (C < 320) { wp = ww_w + (size_t)(C - 192) * 512; bv = ww_b[C - 192]; }
    else              { wp = bf_w + (size_t)(C - 320) * 512; bv = bf_b[C - 320]; }
    float dot = 0.f;
#pragma unroll 8
    for (int k = 0; k < 512; k += 4) {
      fx4 w = *(const fx4*)(wp + k);
      dot += hrow[k] * w[0] + hrow[k + 1] * w[1] + hrow[k + 2] * w[2] + hrow[k + 3] * w[3];
    }
    const float res = bv + dot;
    if (C < 32)       out[(size_t)b_ * 32 + C] = __builtin_amdgcn_exp2f(res * 1.44269504f) * 0.1f;
    else if (C < 64)  out[32768 + (size_t)b_ * 32 + (C - 32)] = res - 5.f;
    else if (C < 192) out[65536 + (size_t)b_ * 128 + (C - 64)] = res;
    else if (C < 320) out[196608 + (size_t)b_ * 128 + (C - 192)] = res;
    else              out[327680 + (size_t)b_ * 4 + (C - 320)] = res;
  }
}

extern "C" void kernel_launch(void* const* d_in, const int* in_sizes, int n_in,
                              void* d_out, int out_size, void* d_ws, size_t ws_size,
                              hipStream_t stream) {
  (void)in_sizes; (void)n_in; (void)out_size; (void)ws_size;
  const float* x     = (const float*)d_in[0];
  const float* a     = (const float*)d_in[1];
  const float* mask  = (const float*)d_in[2];
  const float* w_ih  = (const float*)d_in[3];
  const float* w_hh  = (const float*)d_in[4];
  const float* b_ih  = (const float*)d_in[5];
  const float* b_hh  = (const float*)d_in[6];
  const float* lin_w = (const float*)d_in[7];
  const float* lin_b = (const float*)d_in[8];
  const float* lv_w  = (const float*)d_in[9];
  const float* lv_b  = (const float*)d_in[10];
  const float* u_w   = (const float*)d_in[11];
  const float* u_b   = (const float*)d_in[12];
  const float* ww_w  = (const float*)d_in[13];
  const float* ww_b  = (const float*)d_in[14];
  const float* bf_w  = (const float*)d_in[15];
  const float* bf_b  = (const float*)d_in[16];

  char* ws = (char*)d_ws;
  short* yw       = (short*)(ws);                 // 33,554,432 B: [256][1024][64] bf16
  short* hbuf     = (short*)(ws + 33554432);      //  2,097,152 B: [2][1024][512] bf16
  float* hfinal   = (float*)(ws + 35651584);      //  2,097,152 B
  unsigned* ctr   = (unsigned*)(ws + 37748736);   //     36,864 B (flags region)

  hipMemsetAsync(ctr, 0, 36864, stream);          // flags only; hbuf kernel-written

  pack_y_kernel<<<1024, 256, 0, stream>>>(x, a, mask, yw);
  lstm_rec<<<256, 256, 0, stream>>>(yw, w_hh, w_ih, b_ih, b_hh, hbuf, hfinal, ctr);
  heads_kernel<<<dim3(16, 6), 256, 0, stream>>>(hfinal, lin_w, lin_b, lv_w, lv_b,
                                                u_w, u_b, ww_w, ww_b, bf_w, bf_b,
                                                (float*)d_out);
}

// Round 14
// 1395.570 us; speedup vs baseline: 1.2651x; 1.0741x over previous
//
#include <hip/hip_runtime.h>

// EncoderPlanarLSTM: T=256,B=1024,DX=48,DA=16 (I=64), H=512, Z=32, F=4
// out = [mu(1024x32) | log_var(1024x32) | u(1024x128) | w(1024x128) | b(1024x4)] fp32
//
// R14 = R13 with h-data at sc0-only (XCD-L2-resident, writeback; no HBM write-through).
// Flags remain sc0 sc1 (MALL) for graph-replay-safe memset coherence. Groups are
// same-XCD by the R10 FETCH-validated mapping (xcd = wg%8), so sc0 h exchange is
// producer/consumer-coherent through the shared per-XCD L2.

typedef __attribute__((__ext_vector_type__(8))) short bx8;   // 8 bf16 (4 VGPR)
typedef __attribute__((__ext_vector_type__(4))) float fx4;
typedef __attribute__((__ext_vector_type__(4))) unsigned ux4;
typedef unsigned long long u64;

#define NKT   18          // K-tiles of 32 over K=576 (512 h + 64 y)
#define ROWB  1184        // LDS bytes per A row (1152 data + 32 pad)
#define GREG  18944       // per-group LDS region: 16 rows * 1184
#define TRPO  37888       // transpose slabs at 2*GREG

__device__ __forceinline__ short bf16_of(float f) {
  union { float f; unsigned u; } c; c.f = f;
  unsigned r = c.u + 0x7fffu + ((c.u >> 16) & 1u);   // RNE
  return (short)(r >> 16);
}
__device__ __forceinline__ float fsigmoid(float x) {
  float e = __builtin_amdgcn_exp2f(-1.44269504f * x);
  return __builtin_amdgcn_rcpf(1.0f + e);
}
__device__ __forceinline__ float ftanh_(float x) {
  float e = __builtin_amdgcn_exp2f(2.88539008f * x);
  return 1.0f - 2.0f * __builtin_amdgcn_rcpf(1.0f + e);
}

__device__ __forceinline__ void poll_flags(const unsigned* p, unsigned tgt) {
  unsigned guard = 0;
  for (;;) {
    unsigned v;
    asm volatile("global_load_dword %0, %1, off sc0 sc1\n\ts_waitcnt vmcnt(0)"
                 : "=v"(v) : "v"(p) : "memory");
    if (__all((int)(v >= tgt))) break;
    if (++guard > (1u << 16)) break;      // bail: terminate, never hang
  }
}

// ---------------- pack masked+concat input to bf16, natural time order -------
__global__ __launch_bounds__(256) void pack_y_kernel(
    const float* __restrict__ x, const float* __restrict__ a,
    const float* __restrict__ mk, short* __restrict__ y) {
  const int idx = blockIdx.x * 256 + threadIdx.x;
  const float* xp = x + (size_t)idx * 48;
  const float* mp = mk + (size_t)idx * 48;
  const float* ap = a + (size_t)idx * 16;
  short* yp = y + (size_t)idx * 64;
  float v[64];
#pragma unroll
  for (int j = 0; j < 12; ++j) {
    fx4 xv = *(const fx4*)(xp + j * 4);
    fx4 mv = *(const fx4*)(mp + j * 4);
#pragma unroll
    for (int t = 0; t < 4; ++t) v[j * 4 + t] = xv[t] * mv[t];
  }
#pragma unroll
  for (int j = 0; j < 4; ++j) {
    fx4 av = *(const fx4*)(ap + j * 4);
#pragma unroll
    for (int t = 0; t < 4; ++t) v[48 + j * 4 + t] = av[t];
  }
#pragma unroll
  for (int c = 0; c < 8; ++c) {
    bx8 o;
#pragma unroll
    for (int t = 0; t < 8; ++t) o[t] = bf16_of(v[c * 8 + t]);
    *(bx8*)(yp + c * 8) = o;
  }
}

// ---------------- compute one group: MFMA + gates + trp/hfinal ---------------
__device__ __forceinline__ void compute_grp(
    bool fin, char* Ash, int reg, char* trp,
    const bx8* Bf, const float* bias, float* cst,
    int g, int colh, int wv, int l15, int l4, unsigned xm,
    float* __restrict__ hfinal)
{
  fx4 acc[4];
#pragma unroll
  for (int nt = 0; nt < 4; ++nt) {
    fx4 z = {bias[nt], bias[nt], bias[nt], bias[nt]};
    acc[nt] = z;
  }
  const char* abase = Ash + reg + l15 * ROWB;
  const unsigned kbase = (unsigned)(l4 * 16);
#pragma unroll
  for (int kt = 0; kt < NKT; ++kt) {
    bx8 A0 = *(const bx8*)(abase + (int)(((unsigned)(kt * 64) + kbase) ^ xm));
#pragma unroll
    for (int nt = 0; nt < 4; ++nt)
      acc[nt] = __builtin_amdgcn_mfma_f32_16x16x32_bf16(A0, Bf[nt * NKT + kt], acc[nt], 0, 0, 0);
  }
#pragma unroll
  for (int r = 0; r < 4; ++r) {
    float gi = acc[0][r], gf = acc[1][r], gg = acc[2][r], go = acc[3][r];
    float c = fsigmoid(gf) * cst[r] + fsigmoid(gi) * ftanh_(gg);
    cst[r] = c;
    float h = fsigmoid(go) * ftanh_(c);
    if (fin) {
      hfinal[(size_t)(g * 16 + l4 * 4 + r) * 512 + colh] = h;
    } else {
      *(unsigned short*)(trp + (l4 * 4 + r) * 128 + (wv * 16 + l15) * 2) =
          (unsigned short)bf16_of(h);
    }
  }
}

// ---------------- recurrent LSTM: merged per-step exchange, L2-local h -------
__global__ __launch_bounds__(256, 1) void lstm_rec(
    const short* __restrict__ yw,      // [256][1024][64] bf16
    const float* __restrict__ w_hh,    // [2048][512]
    const float* __restrict__ w_ih,    // [2048][64]
    const float* __restrict__ b_ih, const float* __restrict__ b_hh,
    short* hbuf,                       // [2][1024][512] bf16
    float* __restrict__ hfinal,        // [1024][512]
    unsigned* ctr)                     // flag words at u32[1024 + (gA*8+gn)*16]
{
  __shared__ __align__(16) char Ash[82432];   // >81920 -> exactly 1 WG/CU
  const int tid = threadIdx.x;
  const int wg  = blockIdx.x;
  // XCD-local mapping (R10 FETCH-validated): all 8 slices of a pod on one XCD
  const int xcd = wg & 7;
  const int ii  = wg >> 3;
  const int gn  = ii & 7;              // 64-col slice
  const int q   = ii >> 3;             // pod 0..3 within XCD
  const int gA  = xcd * 4 + q;         // 0..31
  const int gB  = gA + 32;
  const int wv  = tid >> 6;
  const int lane = tid & 63;
  const int l15 = lane & 15;
  const int l4  = lane >> 4;

  // ---- resident weights: 4 gates x 18 kt, cols gn*64 + wv*16 + l15 ----
  bx8 Bf[4 * NKT];
  float bias[4];
  const int colh = gn * 64 + wv * 16 + l15;
#pragma unroll
  for (int nt = 0; nt < 4; ++nt) {
    const int col = nt * 512 + colh;
    bias[nt] = b_ih[col] + b_hh[col];
#pragma unroll
    for (int kt = 0; kt < NKT; ++kt) {
      const int k0 = kt * 32 + l4 * 8;
      const float* src = (k0 < 512) ? (w_hh + (size_t)col * 512 + k0)
                                    : (w_ih + (size_t)col * 64 + (k0 - 512));
      fx4 w0 = *(const fx4*)(src);
      fx4 w1 = *(const fx4*)(src + 4);
      bx8 b;
#pragma unroll
      for (int t = 0; t < 4; ++t) { b[t] = bf16_of(w0[t]); b[4 + t] = bf16_of(w1[t]); }
      Bf[nt * NKT + kt] = b;
    }
  }

  float cstA[4], cstB[4];
#pragma unroll
  for (int i = 0; i < 4; ++i) { cstA[i] = 0.f; cstB[i] = 0.f; }

  const int srow = tid >> 4;           // 0..15: staging/publish row
  const int sch  = tid & 15;
  const unsigned xsw = (unsigned)((srow & 7) << 4);
  const unsigned xm  = (unsigned)((l15 & 7) << 4);
  char* trpA = Ash + TRPO;
  char* trpB = Ash + TRPO + 2048;

  unsigned* flbase = ctr + 1024;
  unsigned* myflag = flbase + (gA * 8 + gn) * 16;
  const unsigned* pollp = flbase + (gA * 8 + (lane & 7)) * 16;

  // ---- prologue: stage regA/regB = zeros (h(0)=0) + y(255); no hbuf read ----
  {
    const char* ysl = (const char*)yw + (size_t)255 * 131072;
#pragma unroll
    for (int g2 = 0; g2 < 2; ++g2) {
      const int g = g2 ? gB : gA;
      const int reg = g2 ? GREG : 0;
      u64 vy = *(const u64*)(ysl + (size_t)(g * 16 + srow) * 128 + sch * 8);
      char* lb = Ash + reg + srow * ROWB;
      ux4 z = {0u, 0u, 0u, 0u};
#pragma unroll
      for (int j = 0; j < 4; ++j)
        *(ux4*)(lb + (int)(((unsigned)(sch * 16 + j * 256)) ^ xsw)) = z;
      *(u64*)(lb + (int)((1024u + sch * 8) ^ xsw)) = vy;
    }
    asm volatile("s_waitcnt lgkmcnt(0)" ::: "memory");
    __builtin_amdgcn_sched_barrier(0);
    __builtin_amdgcn_s_barrier();
  }

#pragma unroll 1
  for (int s = 0; s < 256; ++s) {
    const bool last = (s == 255);

    // early y loads for step s+1 (plain, compiler-tracked; hide under MFMA)
    const char* ynx = (const char*)yw + (size_t)(last ? 0 : 254 - s) * 131072;
    u64 vyA = *(const u64*)(ynx + (size_t)(gA * 16 + srow) * 128 + sch * 8);
    u64 vyB = *(const u64*)(ynx + (size_t)(gB * 16 + srow) * 128 + sch * 8);

    // compute both groups from staged LDS
    compute_grp(last, Ash, 0,    trpA, Bf, bias, cstA, gA, colh, wv, l15, l4, xm, hfinal);
    compute_grp(last, Ash, GREG, trpB, Bf, bias, cstB, gB, colh, wv, l15, l4, xm, hfinal);
    asm volatile("s_waitcnt lgkmcnt(0)" ::: "memory");
    __builtin_amdgcn_sched_barrier(0);
    __builtin_amdgcn_s_barrier();

    if (!last) {
      char* slot = (char*)hbuf + (size_t)((s + 1) & 1) * 1048576;

      // ---- publish h_A(s+1), h_B(s+1): sc0-only -> XCD L2 writeback, fast ack ----
      u64 pA = *(const u64*)(trpA + srow * 128 + sch * 8);
      u64 pB = *(const u64*)(trpB + srow * 128 + sch * 8);
      char* sbA = slot + (size_t)(gA * 16 + srow) * 1024 + gn * 128 + sch * 8;
      char* sbB = slot + (size_t)(gB * 16 + srow) * 1024 + gn * 128 + sch * 8;
      asm volatile("global_store_dwordx2 %0, %1, off sc0" :: "v"(sbA), "v"(pA) : "memory");
      asm volatile("global_store_dwordx2 %0, %1, off sc0" :: "v"(sbB), "v"(pB) : "memory");
      asm volatile("s_waitcnt vmcnt(0)" ::: "memory");   // acked at local L2
      __builtin_amdgcn_s_barrier();                      // WG-wide publish complete

      // ---- one flag + one poll per step (MALL: replay-safe with memset) ----
      if (tid == 0) {
        unsigned sv = (unsigned)(s + 1);
        asm volatile("global_store_dword %0, %1, off sc0 sc1" :: "v"(myflag), "v"(sv) : "memory");
      }
      poll_flags(pollp, (unsigned)(s + 1));

      // ---- load h(s+1) for both groups: sc0 (L2 hit; poll precedes issue) ----
      const char* hqA = slot + (size_t)(gA * 16 + srow) * 1024 + sch * 16;
      const char* hqB = slot + (size_t)(gB * 16 + srow) * 1024 + sch * 16;
      ux4 a0, a1, a2, a3, b0, b1, b2, b3;
      asm volatile("global_load_dwordx4 %0, %1, off sc0" : "=v"(a0) : "v"(hqA) : "memory");
      asm volatile("global_load_dwordx4 %0, %1, off offset:256 sc0" : "=v"(a1) : "v"(hqA) : "memory");
      asm volatile("global_load_dwordx4 %0, %1, off offset:512 sc0" : "=v"(a2) : "v"(hqA) : "memory");
      asm volatile("global_load_dwordx4 %0, %1, off offset:768 sc0" : "=v"(a3) : "v"(hqA) : "memory");
      asm volatile("global_load_dwordx4 %0, %1, off sc0" : "=v"(b0) : "v"(hqB) : "memory");
      asm volatile("global_load_dwordx4 %0, %1, off offset:256 sc0" : "=v"(b1) : "v"(hqB) : "memory");
      asm volatile("global_load_dwordx4 %0, %1, off offset:512 sc0" : "=v"(b2) : "v"(hqB) : "memory");
      asm volatile("global_load_dwordx4 %0, %1, off offset:768 sc0" : "=v"(b3) : "v"(hqB) : "memory");
      asm volatile("s_waitcnt vmcnt(0)" ::: "memory");
      __builtin_amdgcn_sched_barrier(0);

      // ---- stage both groups + y into LDS (R10-proven layout/swizzle) ----
      char* lbA = Ash + srow * ROWB;
      char* lbB = Ash + GREG + srow * ROWB;
      *(ux4*)(lbA + (int)(((unsigned)(sch * 16 + 0))   ^ xsw)) = a0;
      *(ux4*)(lbA + (int)(((unsigned)(sch * 16 + 256)) ^ xsw)) = a1;
      *(ux4*)(lbA + (int)(((unsigned)(sch * 16 + 512)) ^ xsw)) = a2;
      *(ux4*)(lbA + (int)(((unsigned)(sch * 16 + 768)) ^ xsw)) = a3;
      *(u64*)(lbA + (int)((1024u + sch * 8) ^ xsw)) = vyA;
      *(ux4*)(lbB + (int)(((unsigned)(sch * 16 + 0))   ^ xsw)) = b0;
      *(ux4*)(lbB + (int)(((unsigned)(sch * 16 + 256)) ^ xsw)) = b1;
      *(ux4*)(lbB + (int)(((unsigned)(sch * 16 + 512)) ^ xsw)) = b2;
      *(ux4*)(lbB + (int)(((unsigned)(sch * 16 + 768)) ^ xsw)) = b3;
      *(u64*)(lbB + (int)((1024u + sch * 8) ^ xsw)) = vyB;
      asm volatile("s_waitcnt lgkmcnt(0)" ::: "memory");
      __builtin_amdgcn_sched_barrier(0);
      __builtin_amdgcn_s_barrier();
    }
  }
}

// ---------------- heads: exact fp32 VALU GEMM [1024 x 324 x 512] + epilogue --
__global__ __launch_bounds__(256) void heads_kernel(
    const float* __restrict__ hf,
    const float* __restrict__ lin_w, const float* __restrict__ lin_b,
    const float* __restrict__ lv_w,  const float* __restrict__ lv_b,
    const float* __restrict__ u_w,   const float* __restrict__ u_b,
    const float* __restrict__ ww_w,  const float* __restrict__ ww_b,
    const float* __restrict__ bf_w,  const float* __restrict__ bf_b,
    float* __restrict__ out)
{
  __shared__ float hs[64 * 513];
  const int tid = threadIdx.x;
  const int gb = blockIdx.x;     // 0..15
  const int cg = blockIdx.y;     // 0..5, 54 cols each
  for (int i = tid; i < 8192; i += 256) {
    fx4 v = *(const fx4*)(hf + (size_t)gb * 32768 + (size_t)i * 4);
    const int row = i >> 7;
    const int k = (i * 4) & 511;
    float* d = hs + row * 513 + k;
    d[0] = v[0]; d[1] = v[1]; d[2] = v[2]; d[3] = v[3];
  }
  __syncthreads();
  const int r = tid & 63;
  const int cq = tid >> 6;
  const float* hrow = hs + r * 513;
  const int b_ = gb * 64 + r;
#pragma unroll 1
  for (int j = 0; j < 14; ++j) {
    const int cl = cq + 4 * j;
    if (cl >= 54) break;
    const int C = cg * 54 + cl;      // 0..323
    const float* wp; float bv;
    if (C < 32)       { wp = lin_w + (size_t)C * 512;        bv = lin_b[C]; }
    else if (C < 64)  { wp = lv_w + (size_t)(C - 32) * 512;  bv = lv_b[C - 32]; }
    else if (C < 192) { wp = u_w + (size_t)(C - 64) * 512;   bv = u_b[C - 64]; }
    else if (C < 320) { wp = ww_w + (size_t)(C - 192) * 512; bv = ww_b[C - 192]; }
    else              { wp = bf_w + (size_t)(C - 320) * 512; bv = bf_b[C - 320]; }
    float dot = 0.f;
#pragma unroll 8
    for (int k = 0; k < 512; k += 4) {
      fx4 w = *(const fx4*)(wp + k);
      dot += hrow[k] * w[0] + hrow[k + 1] * w[1] + hrow[k + 2] * w[2] + hrow[k + 3] * w[3];
    }
    const float res = bv + dot;
    if (C < 32)       out[(size_t)b_ * 32 + C] = __builtin_amdgcn_exp2f(res * 1.44269504f) * 0.1f;
    else if (C < 64)  out[32768 + (size_t)b_ * 32 + (C - 32)] = res - 5.f;
    else if (C < 192) out[65536 + (size_t)b_ * 128 + (C - 64)] = res;
    else if (C < 320) out[196608 + (size_t)b_ * 128 + (C - 192)] = res;
    else              out[327680 + (size_t)b_ * 4 + (C - 320)] = res;
  }
}

extern "C" void kernel_launch(void* const* d_in, const int* in_sizes, int n_in,
                              void* d_out, int out_size, void* d_ws, size_t ws_size,
                              hipStream_t stream) {
  (void)in_sizes; (void)n_in; (void)out_size; (void)ws_size;
  const float* x     = (const float*)d_in[0];
  const float* a     = (const float*)d_in[1];
  const float* mask  = (const float*)d_in[2];
  const float* w_ih  = (const float*)d_in[3];
  const float* w_hh  = (const float*)d_in[4];
  const float* b_ih  = (const float*)d_in[5];
  const float* b_hh  = (const float*)d_in[6];
  const float* lin_w = (const float*)d_in[7];
  const float* lin_b = (const float*)d_in[8];
  const float* lv_w  = (const float*)d_in[9];
  const float* lv_b  = (const float*)d_in[10];
  const float* u_w   = (const float*)d_in[11];
  const float* u_b   = (const float*)d_in[12];
  const float* ww_w  = (const float*)d_in[13];
  const float* ww_b  = (const float*)d_in[14];
  const float* bf_w  = (const float*)d_in[15];
  const float* bf_b  = (const float*)d_in[16];

  char* ws = (char*)d_ws;
  short* yw       = (short*)(ws);                 // 33,554,432 B: [256][1024][64] bf16
  short* hbuf     = (short*)(ws + 33554432);      //  2,097,152 B: [2][1024][512] bf16
  float* hfinal   = (float*)(ws + 35651584);      //  2,097,152 B
  unsigned* ctr   = (unsigned*)(ws + 37748736);   //     36,864 B (flags region)

  hipMemsetAsync(hbuf, 0, 2097152, stream);       // deterministic baseline
  hipMemsetAsync(ctr, 0, 36864, stream);

  pack_y_kernel<<<1024, 256, 0, stream>>>(x, a, mask, yw);
  lstm_rec<<<256, 256, 0, stream>>>(yw, w_hh, w_ih, b_ih, b_hh, hbuf, hfinal, ctr);
  heads_kernel<<<dim3(16, 6), 256, 0, stream>>>(hfinal, lin_w, lin_b, lv_w, lv_b,
                                                u_w, u_b, ww_w, ww_b, bf_w, bf_b,
                                                (float*)d_out);
}